// Round 1
// baseline (3424.612 us; speedup 1.0000x reference)
//
#include <hip/hip_runtime.h>
#include <math.h>

#define NN 50000
#define TT 16
#define DD 128

// ---------- graph preprocessing ----------

__global__ void k_deg_init(int* __restrict__ deg) {
  int i = blockIdx.x * blockDim.x + threadIdx.x;
  if (i < NN) deg[i] = 1;  // self loop
}

__global__ void k_deg_count(const int* __restrict__ dst, int* __restrict__ deg, int e) {
  int i = blockIdx.x * blockDim.x + threadIdx.x;
  if (i < e) atomicAdd(&deg[dst[i]], 1);
}

__global__ void k_dinv(const int* __restrict__ deg, float* __restrict__ dinv) {
  int i = blockIdx.x * blockDim.x + threadIdx.x;
  if (i < NN) dinv[i] = rsqrtf((float)deg[i]);
}

// exclusive scan over (deg-1) -> rowptr, single block
__global__ __launch_bounds__(1024) void k_scan(const int* __restrict__ deg, int* __restrict__ rowptr) {
  __shared__ int sm[1024];
  __shared__ int running;
  int tid = threadIdx.x;
  if (tid == 0) running = 0;
  __syncthreads();
  for (int base = 0; base < NN; base += 1024) {
    int i = base + tid;
    int v = (i < NN) ? (deg[i] - 1) : 0;
    sm[tid] = v;
    __syncthreads();
    for (int off = 1; off < 1024; off <<= 1) {
      int t = (tid >= off) ? sm[tid - off] : 0;
      __syncthreads();
      sm[tid] += t;
      __syncthreads();
    }
    if (i < NN) rowptr[i] = running + sm[tid] - v;  // exclusive
    int bs = sm[1023];
    __syncthreads();
    if (tid == 0) running += bs;
    __syncthreads();
  }
  if (tid == 0) rowptr[NN] = running;
}

__global__ void k_fill(const int* __restrict__ src, const int* __restrict__ dst,
                       const int* __restrict__ rowptr, int* __restrict__ cur,
                       int* __restrict__ col, int e) {
  int i = blockIdx.x * blockDim.x + threadIdx.x;
  if (i < e) {
    int d = dst[i];
    int slot = atomicAdd(&cur[d], 1);
    col[rowptr[d] + slot] = src[i];
  }
}

__global__ void k_bsum(const float* __restrict__ bc, const float* __restrict__ bl,
                       float* __restrict__ bsum) {
  int i = threadIdx.x;
  if (i < DD) bsum[i] = bc[i] + bl[i];
}

// ---------- GEMM: [M x 128] @ [128 x 128], 128x128 tile, 8x8 reg blocking ----------
// MODE 0: Y[row] = (A[row] @ W) * dinv[row]          (xw -> y, pre-scaled)
// MODE 1: Y[row] = tanh(A[row] @ W + agg[row] + bsum) (recurrence step)
template<int MODE>
__global__ __launch_bounds__(256) void k_gemm(
    const float* __restrict__ Abase, long lda,
    const float* __restrict__ W,
    const float* __restrict__ dinv,
    const float* __restrict__ agg,
    const float* __restrict__ bsum,
    float* __restrict__ Y, long ldy, int M)
{
  __shared__ float sA[128 * 132];  // transposed: sA[k*132 + r], pad 132
  const int tid = threadIdx.x;
  const int row0 = blockIdx.x * 128;

  // stage A tile transposed: thread -> r = tid/2, half = tid%2 (64 k each)
  {
    int r = tid >> 1, half = tid & 1;
    int row = row0 + r;
    const float* ap = Abase + (long)row * lda + half * 64;
    #pragma unroll
    for (int i = 0; i < 16; ++i) {
      float4 v = make_float4(0.f, 0.f, 0.f, 0.f);
      if (row < M) v = *(const float4*)(ap + i * 4);
      int k = half * 64 + i * 4;
      sA[(k + 0) * 132 + r] = v.x;
      sA[(k + 1) * 132 + r] = v.y;
      sA[(k + 2) * 132 + r] = v.z;
      sA[(k + 3) * 132 + r] = v.w;
    }
  }
  __syncthreads();

  const int c0 = (tid & 15) * 8;
  const int r0 = (tid >> 4) * 8;
  float acc[8][8];
  #pragma unroll
  for (int i = 0; i < 8; ++i)
    #pragma unroll
    for (int j = 0; j < 8; ++j) acc[i][j] = 0.f;

  #pragma unroll 8
  for (int k = 0; k < 128; ++k) {
    float4 w0 = *(const float4*)&W[k * 128 + c0];
    float4 w1 = *(const float4*)&W[k * 128 + c0 + 4];
    float4 a0 = *(const float4*)&sA[k * 132 + r0];
    float4 a1 = *(const float4*)&sA[k * 132 + r0 + 4];
    float ar[8] = {a0.x, a0.y, a0.z, a0.w, a1.x, a1.y, a1.z, a1.w};
    float wr[8] = {w0.x, w0.y, w0.z, w0.w, w1.x, w1.y, w1.z, w1.w};
    #pragma unroll
    for (int i = 0; i < 8; ++i)
      #pragma unroll
      for (int j = 0; j < 8; ++j)
        acc[i][j] = fmaf(ar[i], wr[j], acc[i][j]);
  }

  #pragma unroll
  for (int i = 0; i < 8; ++i) {
    int row = row0 + r0 + i;
    if (row >= M) continue;
    float o[8];
    if (MODE == 0) {
      float s = dinv[row];
      #pragma unroll
      for (int j = 0; j < 8; ++j) o[j] = acc[i][j] * s;
    } else {
      #pragma unroll
      for (int j = 0; j < 8; ++j)
        o[j] = tanhf(acc[i][j] + agg[(long)row * DD + c0 + j] + bsum[c0 + j]);
    }
    float* yp = Y + (long)row * ldy + c0;
    *(float4*)(yp)     = make_float4(o[0], o[1], o[2], o[3]);
    *(float4*)(yp + 4) = make_float4(o[4], o[5], o[6], o[7]);
  }
}

// ---------- CSR gather: agg[n] = dinv[n] * (sum_{in-edges} y[src] + y[n]) ----------
__global__ __launch_bounds__(256) void k_gather(
    const float* __restrict__ y, const int* __restrict__ col,
    const int* __restrict__ rowptr, const float* __restrict__ dinv,
    float* __restrict__ agg)
{
  int wave = threadIdx.x >> 6;
  int lane = threadIdx.x & 63;
  int n = blockIdx.x * 4 + wave;
  if (n >= NN) return;
  int beg = rowptr[n], end = rowptr[n + 1];
  const float2* yv = (const float2*)y;
  float2 a0 = yv[(long)n * 64 + lane];  // self-loop term y[n]
  float2 a1 = make_float2(0.f, 0.f);
  float2 a2 = make_float2(0.f, 0.f);
  float2 a3 = make_float2(0.f, 0.f);
  int j = beg;
  for (; j + 4 <= end; j += 4) {
    int s0 = col[j], s1 = col[j + 1], s2 = col[j + 2], s3 = col[j + 3];
    float2 v0 = yv[(long)s0 * 64 + lane];
    float2 v1 = yv[(long)s1 * 64 + lane];
    float2 v2 = yv[(long)s2 * 64 + lane];
    float2 v3 = yv[(long)s3 * 64 + lane];
    a0.x += v0.x; a0.y += v0.y;
    a1.x += v1.x; a1.y += v1.y;
    a2.x += v2.x; a2.y += v2.y;
    a3.x += v3.x; a3.y += v3.y;
  }
  for (; j < end; ++j) {
    int s = col[j];
    float2 v = yv[(long)s * 64 + lane];
    a0.x += v.x; a0.y += v.y;
  }
  float di = dinv[n];
  float2 r;
  r.x = di * (a0.x + a1.x + a2.x + a3.x);
  r.y = di * (a0.y + a1.y + a2.y + a3.y);
  ((float2*)agg)[(long)n * 64 + lane] = r;
}

// t = 0 step: h0 = 0 so no W_lin term
__global__ void k_step0(const float* __restrict__ agg, const float* __restrict__ bsum,
                        float* __restrict__ out) {
  long i = (long)blockIdx.x * blockDim.x + threadIdx.x;
  if (i < (long)NN * DD) {
    int n = (int)(i >> 7);
    int d = (int)(i & 127);
    out[((long)n * TT) * DD + d] = tanhf(agg[i] + bsum[d]);
  }
}

extern "C" void kernel_launch(void* const* d_in, const int* in_sizes, int n_in,
                              void* d_out, int out_size, void* d_ws, size_t ws_size,
                              hipStream_t stream) {
  const float* x  = (const float*)d_in[0];
  const int*   ei = (const int*)d_in[1];
  const float* Wc = (const float*)d_in[2];
  const float* bc = (const float*)d_in[3];
  const float* Wl = (const float*)d_in[4];
  const float* bl = (const float*)d_in[5];
  float* out = (float*)d_out;
  const int E = in_sizes[1] / 2;
  const int* srcp = ei;
  const int* dstp = ei + E;

  char* w = (char*)d_ws;
  auto alloc = [&](size_t bytes) {
    char* p = w;
    w += (bytes + 255) & ~(size_t)255;
    return p;
  };
  int*   deg    = (int*)alloc(sizeof(int) * NN);
  float* dinv   = (float*)alloc(sizeof(float) * NN);
  int*   rowptr = (int*)alloc(sizeof(int) * (NN + 1));
  int*   cur    = (int*)alloc(sizeof(int) * NN);
  int*   col    = (int*)alloc(sizeof(int) * (size_t)E);
  float* y      = (float*)alloc(sizeof(float) * (size_t)NN * DD);
  float* agg    = (float*)alloc(sizeof(float) * (size_t)NN * DD);
  float* bsum   = (float*)alloc(sizeof(float) * DD);

  k_deg_init<<<(NN + 255) / 256, 256, 0, stream>>>(deg);
  k_deg_count<<<(E + 255) / 256, 256, 0, stream>>>(dstp, deg, E);
  k_dinv<<<(NN + 255) / 256, 256, 0, stream>>>(deg, dinv);
  k_scan<<<1, 1024, 0, stream>>>(deg, rowptr);
  hipMemsetAsync(cur, 0, sizeof(int) * NN, stream);
  k_fill<<<(E + 255) / 256, 256, 0, stream>>>(srcp, dstp, rowptr, cur, col, E);
  k_bsum<<<1, 128, 0, stream>>>(bc, bl, bsum);

  const int gblocks = (NN + 127) / 128;
  for (int t = 0; t < TT; ++t) {
    // y = (x_t @ W_conv) * dinv[n]
    k_gemm<0><<<gblocks, 256, 0, stream>>>(x + (long)t * DD, (long)TT * DD, Wc,
                                           dinv, nullptr, nullptr, y, (long)DD, NN);
    // agg = dinv[n] * (sum y[src] + y[n])
    k_gather<<<(NN + 3) / 4, 256, 0, stream>>>(y, col, rowptr, dinv, agg);
    if (t == 0) {
      k_step0<<<(int)(((long)NN * DD + 255) / 256), 256, 0, stream>>>(agg, bsum, out);
    } else {
      // h_t = tanh(agg + bsum + h_{t-1} @ W_lin), h read/written strided in d_out
      k_gemm<1><<<gblocks, 256, 0, stream>>>(out + (long)(t - 1) * DD, (long)TT * DD, Wl,
                                             nullptr, agg, bsum,
                                             out + (long)t * DD, (long)TT * DD, NN);
    }
  }
}

// Round 2
// 2661.869 us; speedup vs baseline: 1.2865x; 1.2865x over previous
//
#include <hip/hip_runtime.h>
#include <math.h>

#define NN 50000
#define TT 16
#define DD 128
#define SCAN_B 1024
#define SCAN_NB ((NN + SCAN_B - 1) / SCAN_B)  // 49

// ---------- bf16 helpers ----------
static __device__ __forceinline__ unsigned short f2bf(float f) {
  unsigned u = __float_as_uint(f);
  u += 0x7FFFu + ((u >> 16) & 1u);  // round-to-nearest-even
  return (unsigned short)(u >> 16);
}
static __device__ __forceinline__ float bf_lo(unsigned v) {
  return __uint_as_float(v << 16);
}
static __device__ __forceinline__ float bf_hi(unsigned v) {
  return __uint_as_float(v & 0xffff0000u);
}

// ---------- graph preprocessing ----------

__global__ void k_deg_init(int* __restrict__ deg) {
  int i = blockIdx.x * blockDim.x + threadIdx.x;
  if (i < NN) deg[i] = 1;  // self loop
}

__global__ void k_deg_count(const int* __restrict__ dst, int* __restrict__ deg, int e) {
  int i = blockIdx.x * blockDim.x + threadIdx.x;
  if (i < e) atomicAdd(&deg[dst[i]], 1);
}

__global__ void k_dinv(const int* __restrict__ deg, float* __restrict__ dinv) {
  int i = blockIdx.x * blockDim.x + threadIdx.x;
  if (i < NN) dinv[i] = rsqrtf((float)deg[i]);
}

// parallel exclusive scan over (deg-1) -> rowptr
__global__ __launch_bounds__(SCAN_B) void k_scan1(const int* __restrict__ deg,
                                                  int* __restrict__ rowptr,
                                                  int* __restrict__ bsums) {
  __shared__ int sm[SCAN_B];
  int tid = threadIdx.x;
  int i = blockIdx.x * SCAN_B + tid;
  int v = (i < NN) ? (deg[i] - 1) : 0;
  sm[tid] = v;
  __syncthreads();
  for (int off = 1; off < SCAN_B; off <<= 1) {
    int t = (tid >= off) ? sm[tid - off] : 0;
    __syncthreads();
    sm[tid] += t;
    __syncthreads();
  }
  if (i < NN) rowptr[i] = sm[tid] - v;  // exclusive, block-local
  if (tid == SCAN_B - 1) bsums[blockIdx.x] = sm[tid];
}

__global__ void k_scan2(int* __restrict__ bsums) {  // 1 block, 64 threads
  __shared__ int sm[64];
  int tid = threadIdx.x;
  int v = (tid < SCAN_NB) ? bsums[tid] : 0;
  sm[tid] = v;
  __syncthreads();
  for (int off = 1; off < 64; off <<= 1) {
    int t = (tid >= off) ? sm[tid - off] : 0;
    __syncthreads();
    sm[tid] += t;
    __syncthreads();
  }
  if (tid < SCAN_NB) bsums[tid] = sm[tid] - v;  // exclusive
  if (tid == 63) bsums[SCAN_NB] = sm[63];       // total
}

__global__ __launch_bounds__(SCAN_B) void k_scan3(int* __restrict__ rowptr,
                                                  const int* __restrict__ bsums) {
  int i = blockIdx.x * SCAN_B + threadIdx.x;
  if (i < NN) rowptr[i] += bsums[blockIdx.x];
  if (i == 0) rowptr[NN] = bsums[SCAN_NB];
}

__global__ void k_fill(const int* __restrict__ src, const int* __restrict__ dst,
                       const int* __restrict__ rowptr, int* __restrict__ cur,
                       int* __restrict__ col, int e) {
  int i = blockIdx.x * blockDim.x + threadIdx.x;
  if (i < e) {
    int d = dst[i];
    int slot = atomicAdd(&cur[d], 1);
    col[rowptr[d] + slot] = src[i];
  }
}

__global__ void k_bsum(const float* __restrict__ bc, const float* __restrict__ bl,
                       float* __restrict__ bsum) {
  int i = threadIdx.x;
  if (i < DD) bsum[i] = bc[i] + bl[i];
}

// ---------- GEMM: [M x 128] @ [128 x 128], 128x128 tile, 8x8 reg blocking ----------
// MODE 0: Ybf[row] = bf16( (A[row] @ W) * dinv[row] )   (xw -> y, pre-scaled, bf16)
// MODE 1: Y[row]   = tanh(A[row] @ W + agg[row] + bsum) (recurrence step, fp32)
template<int MODE>
__global__ __launch_bounds__(256) void k_gemm(
    const float* __restrict__ Abase, long lda,
    const float* __restrict__ W,
    const float* __restrict__ dinv,
    const float* __restrict__ agg,
    const float* __restrict__ bsum,
    float* __restrict__ Y, long ldy,
    unsigned* __restrict__ Ybf, int M)
{
  __shared__ float sA[128 * 132];  // transposed: sA[k*132 + r], pad 132
  const int tid = threadIdx.x;
  const int row0 = blockIdx.x * 128;

  {
    int r = tid >> 1, half = tid & 1;
    int row = row0 + r;
    const float* ap = Abase + (long)row * lda + half * 64;
    #pragma unroll
    for (int i = 0; i < 16; ++i) {
      float4 v = make_float4(0.f, 0.f, 0.f, 0.f);
      if (row < M) v = *(const float4*)(ap + i * 4);
      int k = half * 64 + i * 4;
      sA[(k + 0) * 132 + r] = v.x;
      sA[(k + 1) * 132 + r] = v.y;
      sA[(k + 2) * 132 + r] = v.z;
      sA[(k + 3) * 132 + r] = v.w;
    }
  }
  __syncthreads();

  const int c0 = (tid & 15) * 8;
  const int r0 = (tid >> 4) * 8;
  float acc[8][8];
  #pragma unroll
  for (int i = 0; i < 8; ++i)
    #pragma unroll
    for (int j = 0; j < 8; ++j) acc[i][j] = 0.f;

  #pragma unroll 8
  for (int k = 0; k < 128; ++k) {
    float4 w0 = *(const float4*)&W[k * 128 + c0];
    float4 w1 = *(const float4*)&W[k * 128 + c0 + 4];
    float4 a0 = *(const float4*)&sA[k * 132 + r0];
    float4 a1 = *(const float4*)&sA[k * 132 + r0 + 4];
    float ar[8] = {a0.x, a0.y, a0.z, a0.w, a1.x, a1.y, a1.z, a1.w};
    float wr[8] = {w0.x, w0.y, w0.z, w0.w, w1.x, w1.y, w1.z, w1.w};
    #pragma unroll
    for (int i = 0; i < 8; ++i)
      #pragma unroll
      for (int j = 0; j < 8; ++j)
        acc[i][j] = fmaf(ar[i], wr[j], acc[i][j]);
  }

  #pragma unroll
  for (int i = 0; i < 8; ++i) {
    int row = row0 + r0 + i;
    if (row >= M) continue;
    if (MODE == 0) {
      float s = dinv[row];
      unsigned up[4];
      #pragma unroll
      for (int p = 0; p < 4; ++p) {
        unsigned lo = f2bf(acc[i][2 * p] * s);
        unsigned hi = f2bf(acc[i][2 * p + 1] * s);
        up[p] = lo | (hi << 16);
      }
      unsigned* yp = Ybf + (long)row * 64 + (c0 >> 1);
      *(uint4*)yp = make_uint4(up[0], up[1], up[2], up[3]);
    } else {
      float o[8];
      #pragma unroll
      for (int j = 0; j < 8; ++j)
        o[j] = tanhf(acc[i][j] + agg[(long)row * DD + c0 + j] + bsum[c0 + j]);
      float* yp = Y + (long)row * ldy + c0;
      *(float4*)(yp)     = make_float4(o[0], o[1], o[2], o[3]);
      *(float4*)(yp + 4) = make_float4(o[4], o[5], o[6], o[7]);
    }
  }
}

// ---------- CSR gather (bf16 y): agg[n] = dinv[n] * (sum_{in-edges} y[src] + y[n]) ----------
__global__ __launch_bounds__(256) void k_gather(
    const unsigned* __restrict__ y, const int* __restrict__ col,
    const int* __restrict__ rowptr, const float* __restrict__ dinv,
    float* __restrict__ agg)
{
  int wave = threadIdx.x >> 6;
  int lane = threadIdx.x & 63;
  int n = blockIdx.x * 4 + wave;
  if (n >= NN) return;
  int beg = rowptr[n], end = rowptr[n + 1];
  unsigned su = y[(long)n * 64 + lane];  // self-loop term
  float ax = bf_lo(su), ay = bf_hi(su);
  float bx = 0.f, by = 0.f, cx = 0.f, cy = 0.f, dx = 0.f, dy = 0.f;
  int j = beg;
  for (; j + 4 <= end; j += 4) {
    int s0 = col[j], s1 = col[j + 1], s2 = col[j + 2], s3 = col[j + 3];
    unsigned v0 = y[(long)s0 * 64 + lane];
    unsigned v1 = y[(long)s1 * 64 + lane];
    unsigned v2 = y[(long)s2 * 64 + lane];
    unsigned v3 = y[(long)s3 * 64 + lane];
    ax += bf_lo(v0); ay += bf_hi(v0);
    bx += bf_lo(v1); by += bf_hi(v1);
    cx += bf_lo(v2); cy += bf_hi(v2);
    dx += bf_lo(v3); dy += bf_hi(v3);
  }
  for (; j < end; ++j) {
    unsigned v = y[(long)col[j] * 64 + lane];
    ax += bf_lo(v); ay += bf_hi(v);
  }
  float di = dinv[n];
  float2 r;
  r.x = di * (ax + bx + cx + dx);
  r.y = di * (ay + by + cy + dy);
  ((float2*)agg)[(long)n * 64 + lane] = r;
}

// t = 0 step: h0 = 0 so no W_lin term
__global__ void k_step0(const float* __restrict__ agg, const float* __restrict__ bsum,
                        float* __restrict__ out) {
  long i = (long)blockIdx.x * blockDim.x + threadIdx.x;
  if (i < (long)NN * DD) {
    int n = (int)(i >> 7);
    int d = (int)(i & 127);
    out[((long)n * TT) * DD + d] = tanhf(agg[i] + bsum[d]);
  }
}

extern "C" void kernel_launch(void* const* d_in, const int* in_sizes, int n_in,
                              void* d_out, int out_size, void* d_ws, size_t ws_size,
                              hipStream_t stream) {
  const float* x  = (const float*)d_in[0];
  const int*   ei = (const int*)d_in[1];
  const float* Wc = (const float*)d_in[2];
  const float* bc = (const float*)d_in[3];
  const float* Wl = (const float*)d_in[4];
  const float* bl = (const float*)d_in[5];
  float* out = (float*)d_out;
  const int E = in_sizes[1] / 2;
  const int* srcp = ei;
  const int* dstp = ei + E;

  char* w = (char*)d_ws;
  auto alloc = [&](size_t bytes) {
    char* p = w;
    w += (bytes + 255) & ~(size_t)255;
    return p;
  };
  int*      deg    = (int*)alloc(sizeof(int) * NN);
  float*    dinv   = (float*)alloc(sizeof(float) * NN);
  int*      rowptr = (int*)alloc(sizeof(int) * (NN + 1));
  int*      cur    = (int*)alloc(sizeof(int) * NN);
  int*      bsums  = (int*)alloc(sizeof(int) * (SCAN_NB + 1));
  int*      col    = (int*)alloc(sizeof(int) * (size_t)E);
  unsigned* ybf    = (unsigned*)alloc(sizeof(unsigned) * (size_t)NN * 64);
  float*    agg    = (float*)alloc(sizeof(float) * (size_t)NN * DD);
  float*    bsum   = (float*)alloc(sizeof(float) * DD);

  k_deg_init<<<(NN + 255) / 256, 256, 0, stream>>>(deg);
  k_deg_count<<<(E + 255) / 256, 256, 0, stream>>>(dstp, deg, E);
  k_dinv<<<(NN + 255) / 256, 256, 0, stream>>>(deg, dinv);
  k_scan1<<<SCAN_NB, SCAN_B, 0, stream>>>(deg, rowptr, bsums);
  k_scan2<<<1, 64, 0, stream>>>(bsums);
  k_scan3<<<SCAN_NB, SCAN_B, 0, stream>>>(rowptr, bsums);
  hipMemsetAsync(cur, 0, sizeof(int) * NN, stream);
  k_fill<<<(E + 255) / 256, 256, 0, stream>>>(srcp, dstp, rowptr, cur, col, E);
  k_bsum<<<1, 128, 0, stream>>>(bc, bl, bsum);

  const int gblocks = (NN + 127) / 128;
  for (int t = 0; t < TT; ++t) {
    // y = bf16((x_t @ W_conv) * dinv[n])
    k_gemm<0><<<gblocks, 256, 0, stream>>>(x + (long)t * DD, (long)TT * DD, Wc,
                                           dinv, nullptr, nullptr,
                                           nullptr, 0, ybf, NN);
    // agg = dinv[n] * (sum y[src] + y[n])
    k_gather<<<(NN + 3) / 4, 256, 0, stream>>>(ybf, col, rowptr, dinv, agg);
    if (t == 0) {
      k_step0<<<(int)(((long)NN * DD + 255) / 256), 256, 0, stream>>>(agg, bsum, out);
    } else {
      // h_t = tanh(agg + bsum + h_{t-1} @ W_lin), h read/written strided in d_out
      k_gemm<1><<<gblocks, 256, 0, stream>>>(out + (long)(t - 1) * DD, (long)TT * DD, Wl,
                                             nullptr, agg, bsum,
                                             out + (long)t * DD, (long)TT * DD,
                                             nullptr, NN);
    }
  }
}

// Round 3
// 2423.451 us; speedup vs baseline: 1.4131x; 1.0984x over previous
//
#include <hip/hip_runtime.h>
#include <math.h>

#define NN 50000
#define TT 16
#define DD 128
#define MT (NN * TT)
#define SCAN_B 1024
#define SCAN_NB ((NN + SCAN_B - 1) / SCAN_B)  // 49

typedef __attribute__((ext_vector_type(8))) short short8;
typedef __attribute__((ext_vector_type(4))) float f32x4;
typedef __attribute__((ext_vector_type(2))) float f32x2;

// ---------- bf16 helpers ----------
static __device__ __forceinline__ unsigned short f2bf(float f) {
  unsigned u = __float_as_uint(f);
  u += 0x7FFFu + ((u >> 16) & 1u);  // RNE
  return (unsigned short)(u >> 16);
}
static __device__ __forceinline__ float bf_lo(unsigned v) {
  return __uint_as_float(v << 16);
}
static __device__ __forceinline__ float bf_hi(unsigned v) {
  return __uint_as_float(v & 0xffff0000u);
}

// ---------- graph preprocessing ----------

__global__ void k_deg_init(int* __restrict__ deg) {
  int i = blockIdx.x * blockDim.x + threadIdx.x;
  if (i < NN) deg[i] = 1;  // self loop
}

__global__ void k_deg_count(const int* __restrict__ dst, int* __restrict__ deg, int e) {
  int i = blockIdx.x * blockDim.x + threadIdx.x;
  if (i < e) atomicAdd(&deg[dst[i]], 1);
}

__global__ void k_dinv(const int* __restrict__ deg, float* __restrict__ dinv) {
  int i = blockIdx.x * blockDim.x + threadIdx.x;
  if (i < NN) dinv[i] = rsqrtf((float)deg[i]);
}

__global__ __launch_bounds__(SCAN_B) void k_scan1(const int* __restrict__ deg,
                                                  int* __restrict__ rowptr,
                                                  int* __restrict__ bsums) {
  __shared__ int sm[SCAN_B];
  int tid = threadIdx.x;
  int i = blockIdx.x * SCAN_B + tid;
  int v = (i < NN) ? (deg[i] - 1) : 0;
  sm[tid] = v;
  __syncthreads();
  for (int off = 1; off < SCAN_B; off <<= 1) {
    int t = (tid >= off) ? sm[tid - off] : 0;
    __syncthreads();
    sm[tid] += t;
    __syncthreads();
  }
  if (i < NN) rowptr[i] = sm[tid] - v;
  if (tid == SCAN_B - 1) bsums[blockIdx.x] = sm[tid];
}

__global__ void k_scan2(int* __restrict__ bsums) {
  __shared__ int sm[64];
  int tid = threadIdx.x;
  int v = (tid < SCAN_NB) ? bsums[tid] : 0;
  sm[tid] = v;
  __syncthreads();
  for (int off = 1; off < 64; off <<= 1) {
    int t = (tid >= off) ? sm[tid - off] : 0;
    __syncthreads();
    sm[tid] += t;
    __syncthreads();
  }
  if (tid < SCAN_NB) bsums[tid] = sm[tid] - v;
  if (tid == 63) bsums[SCAN_NB] = sm[63];
}

__global__ __launch_bounds__(SCAN_B) void k_scan3(int* __restrict__ rowptr,
                                                  const int* __restrict__ bsums) {
  int i = blockIdx.x * SCAN_B + threadIdx.x;
  if (i < NN) rowptr[i] += bsums[blockIdx.x];
  if (i == 0) rowptr[NN] = bsums[SCAN_NB];
}

__global__ void k_fill(const int* __restrict__ src, const int* __restrict__ dst,
                       const int* __restrict__ rowptr, int* __restrict__ cur,
                       int* __restrict__ col, int e) {
  int i = blockIdx.x * blockDim.x + threadIdx.x;
  if (i < e) {
    int d = dst[i];
    int slot = atomicAdd(&cur[d], 1);
    col[rowptr[d] + slot] = src[i];
  }
}

__global__ void k_bsum(const float* __restrict__ bc, const float* __restrict__ bl,
                       float* __restrict__ bsum) {
  int i = threadIdx.x;
  if (i < DD) bsum[i] = bc[i] + bl[i];
}

// ---------- GEMM-X (MFMA bf16): Yus[row] = bf16((X[row] @ Wc) * dinv[row>>4]) ----------
// X: [MT][128] fp32 (x flattened [N*T][F]); grid = MT/128 blocks of 256 threads.
__global__ __launch_bounds__(256) void k_gemmx(
    const float* __restrict__ X, const float* __restrict__ Wc,
    const float* __restrict__ dinv, unsigned short* __restrict__ Yus)
{
  __shared__ unsigned short sA[128 * 136];   // sA[r][k], pad 136
  __shared__ unsigned short sWt[128 * 136];  // sWt[n][k] = W[k][n]
  const int tid = threadIdx.x;
  const long row0 = (long)blockIdx.x * 128;

  {
    int r = tid >> 1, half = tid & 1;
    const float* ap = X + (row0 + r) * 128 + half * 64;
    unsigned short* dstp = &sA[r * 136 + half * 64];
    #pragma unroll
    for (int i = 0; i < 16; ++i) {
      float4 v = *(const float4*)(ap + i * 4);
      unsigned u0 = (unsigned)f2bf(v.x) | ((unsigned)f2bf(v.y) << 16);
      unsigned u1 = (unsigned)f2bf(v.z) | ((unsigned)f2bf(v.w) << 16);
      *(uint2*)(dstp + i * 4) = make_uint2(u0, u1);
    }
    int k = tid >> 1, nh = tid & 1;
    const float* wp = Wc + k * 128 + nh * 64;
    #pragma unroll
    for (int i = 0; i < 16; ++i) {
      float4 v = *(const float4*)(wp + i * 4);
      int n = nh * 64 + i * 4;
      sWt[(n + 0) * 136 + k] = f2bf(v.x);
      sWt[(n + 1) * 136 + k] = f2bf(v.y);
      sWt[(n + 2) * 136 + k] = f2bf(v.z);
      sWt[(n + 3) * 136 + k] = f2bf(v.w);
    }
  }
  __syncthreads();

  const int w = tid >> 6, l = tid & 63;
  const int lr = l & 15;
  const int lk = (l >> 4) << 3;
  f32x4 acc[2][8];
  #pragma unroll
  for (int i = 0; i < 2; ++i)
    #pragma unroll
    for (int n = 0; n < 8; ++n) acc[i][n] = (f32x4){0.f, 0.f, 0.f, 0.f};

  #pragma unroll
  for (int kg = 0; kg < 4; ++kg) {
    int kb = kg * 32 + lk;
    short8 a0 = *(const short8*)&sA[(w * 32 + lr) * 136 + kb];
    short8 a1 = *(const short8*)&sA[(w * 32 + 16 + lr) * 136 + kb];
    #pragma unroll
    for (int n = 0; n < 8; ++n) {
      short8 b = *(const short8*)&sWt[(n * 16 + lr) * 136 + kb];
      acc[0][n] = __builtin_amdgcn_mfma_f32_16x16x32_bf16(a0, b, acc[0][n], 0, 0, 0);
      acc[1][n] = __builtin_amdgcn_mfma_f32_16x16x32_bf16(a1, b, acc[1][n], 0, 0, 0);
    }
  }

  // C/D: col = lane&15, row = (lane>>4)*4 + reg  [m89-verified]
  #pragma unroll
  for (int i = 0; i < 2; ++i) {
    long rbase = row0 + w * 32 + i * 16;
    float s = dinv[rbase >> 4];  // row = node*16 + t, TT==16
    #pragma unroll
    for (int n = 0; n < 8; ++n) {
      int colg = n * 16 + lr;
      #pragma unroll
      for (int r = 0; r < 4; ++r) {
        long row = rbase + ((l >> 4) << 2) + r;
        Yus[row * 128 + colg] = f2bf(acc[i][n][r] * s);
      }
    }
  }
}

// ---------- batched gather over all T: agg[n][t] = dinv[n]*(sum_src y[src][t] + y[n][t]) ----------
__global__ __launch_bounds__(256) void k_gatherT(
    const unsigned* __restrict__ Yall,  // [MT][64] uint (2 bf16 each)
    const int* __restrict__ col, const int* __restrict__ rowptr,
    const float* __restrict__ dinv, float* __restrict__ agg)  // [MT][128] fp32
{
  int wave = threadIdx.x >> 6, lane = threadIdx.x & 63;
  int n = blockIdx.x * 4 + wave;
  if (n >= NN) return;
  int beg = rowptr[n], end = rowptr[n + 1];
  float ax[TT], ay[TT];
  {
    const unsigned* sp = Yall + (long)n * (TT * 64) + lane;  // self loop
    #pragma unroll
    for (int t = 0; t < TT; ++t) { unsigned v = sp[t * 64]; ax[t] = bf_lo(v); ay[t] = bf_hi(v); }
  }
  int j = beg;
  for (; j + 2 <= end; j += 2) {
    int s0 = col[j], s1 = col[j + 1];
    const unsigned* p0 = Yall + (long)s0 * (TT * 64) + lane;
    const unsigned* p1 = Yall + (long)s1 * (TT * 64) + lane;
    unsigned v0[TT], v1[TT];
    #pragma unroll
    for (int t = 0; t < TT; ++t) v0[t] = p0[t * 64];
    #pragma unroll
    for (int t = 0; t < TT; ++t) v1[t] = p1[t * 64];
    #pragma unroll
    for (int t = 0; t < TT; ++t) {
      ax[t] += bf_lo(v0[t]) + bf_lo(v1[t]);
      ay[t] += bf_hi(v0[t]) + bf_hi(v1[t]);
    }
  }
  if (j < end) {
    const unsigned* p0 = Yall + (long)col[j] * (TT * 64) + lane;
    #pragma unroll
    for (int t = 0; t < TT; ++t) { unsigned v = p0[t * 64]; ax[t] += bf_lo(v); ay[t] += bf_hi(v); }
  }
  float di = dinv[n];
  f32x2* ap = (f32x2*)(agg + (long)n * (TT * DD)) + lane;
  #pragma unroll
  for (int t = 0; t < TT; ++t) {
    f32x2 r = {di * ax[t], di * ay[t]};
    __builtin_nontemporal_store(r, ap + t * 64);
  }
}

// ---------- recurrence GEMM (fp32 VALU): out_t = tanh(h_{t-1} @ Wl + agg_t + bsum) ----------
// All row strides are TT*DD (strided views into out / agg).
__global__ __launch_bounds__(256) void k_gemmh(
    const float* __restrict__ Abase,  // out + (t-1)*DD
    const float* __restrict__ W,      // Wl
    const float* __restrict__ aggt,   // agg + t*DD
    const float* __restrict__ bsum,
    float* __restrict__ Y)            // out + t*DD
{
  __shared__ float sA[128 * 132];
  const int tid = threadIdx.x;
  const int row0 = blockIdx.x * 128;
  const long LD = (long)TT * DD;

  {
    int r = tid >> 1, half = tid & 1;
    int row = row0 + r;
    const float* ap = Abase + (long)row * LD + half * 64;
    #pragma unroll
    for (int i = 0; i < 16; ++i) {
      float4 v = make_float4(0.f, 0.f, 0.f, 0.f);
      if (row < NN) v = *(const float4*)(ap + i * 4);
      int k = half * 64 + i * 4;
      sA[(k + 0) * 132 + r] = v.x;
      sA[(k + 1) * 132 + r] = v.y;
      sA[(k + 2) * 132 + r] = v.z;
      sA[(k + 3) * 132 + r] = v.w;
    }
  }
  __syncthreads();

  const int c0 = (tid & 15) * 8;
  const int r0 = (tid >> 4) * 8;
  float acc[8][8];
  #pragma unroll
  for (int i = 0; i < 8; ++i)
    #pragma unroll
    for (int j = 0; j < 8; ++j) acc[i][j] = 0.f;

  #pragma unroll 8
  for (int k = 0; k < 128; ++k) {
    float4 w0 = *(const float4*)&W[k * 128 + c0];
    float4 w1 = *(const float4*)&W[k * 128 + c0 + 4];
    float4 a0 = *(const float4*)&sA[k * 132 + r0];
    float4 a1 = *(const float4*)&sA[k * 132 + r0 + 4];
    float ar[8] = {a0.x, a0.y, a0.z, a0.w, a1.x, a1.y, a1.z, a1.w};
    float wr[8] = {w0.x, w0.y, w0.z, w0.w, w1.x, w1.y, w1.z, w1.w};
    #pragma unroll
    for (int i = 0; i < 8; ++i)
      #pragma unroll
      for (int j = 0; j < 8; ++j)
        acc[i][j] = fmaf(ar[i], wr[j], acc[i][j]);
  }

  #pragma unroll
  for (int i = 0; i < 8; ++i) {
    int row = row0 + r0 + i;
    if (row >= NN) continue;
    float o[8];
    #pragma unroll
    for (int j = 0; j < 8; ++j)
      o[j] = tanhf(acc[i][j] + aggt[(long)row * LD + c0 + j] + bsum[c0 + j]);
    float* yp = Y + (long)row * LD + c0;
    *(float4*)(yp)     = make_float4(o[0], o[1], o[2], o[3]);
    *(float4*)(yp + 4) = make_float4(o[4], o[5], o[6], o[7]);
  }
}

// t = 0: h0 = 0, out_0 = tanh(agg_0 + bsum)
__global__ void k_step0(const float* __restrict__ agg, const float* __restrict__ bsum,
                        float* __restrict__ out) {
  long i = (long)blockIdx.x * blockDim.x + threadIdx.x;
  if (i < (long)NN * DD) {
    int n = (int)(i >> 7);
    int d = (int)(i & 127);
    out[(long)n * (TT * DD) + d] = tanhf(agg[(long)n * (TT * DD) + d] + bsum[d]);
  }
}

extern "C" void kernel_launch(void* const* d_in, const int* in_sizes, int n_in,
                              void* d_out, int out_size, void* d_ws, size_t ws_size,
                              hipStream_t stream) {
  const float* x  = (const float*)d_in[0];
  const int*   ei = (const int*)d_in[1];
  const float* Wc = (const float*)d_in[2];
  const float* bc = (const float*)d_in[3];
  const float* Wl = (const float*)d_in[4];
  const float* bl = (const float*)d_in[5];
  float* out = (float*)d_out;
  const int E = in_sizes[1] / 2;
  const int* srcp = ei;
  const int* dstp = ei + E;

  char* w = (char*)d_ws;
  auto alloc = [&](size_t bytes) {
    char* p = w;
    w += (bytes + 255) & ~(size_t)255;
    return p;
  };
  int*      deg    = (int*)alloc(sizeof(int) * NN);
  float*    dinv   = (float*)alloc(sizeof(float) * NN);
  int*      rowptr = (int*)alloc(sizeof(int) * (NN + 1));
  int*      cur    = (int*)alloc(sizeof(int) * NN);
  int*      bsums  = (int*)alloc(sizeof(int) * (SCAN_NB + 1));
  int*      col    = (int*)alloc(sizeof(int) * (size_t)E);
  unsigned* Yall   = (unsigned*)alloc(sizeof(unsigned) * (size_t)MT * 64);   // 204.8 MB
  float*    agg    = (float*)alloc(sizeof(float) * (size_t)MT * DD);         // 409.6 MB
  float*    bsum   = (float*)alloc(sizeof(float) * DD);

  k_deg_init<<<(NN + 255) / 256, 256, 0, stream>>>(deg);
  k_deg_count<<<(E + 255) / 256, 256, 0, stream>>>(dstp, deg, E);
  k_dinv<<<(NN + 255) / 256, 256, 0, stream>>>(deg, dinv);
  k_scan1<<<SCAN_NB, SCAN_B, 0, stream>>>(deg, rowptr, bsums);
  k_scan2<<<1, 64, 0, stream>>>(bsums);
  k_scan3<<<SCAN_NB, SCAN_B, 0, stream>>>(rowptr, bsums);
  hipMemsetAsync(cur, 0, sizeof(int) * NN, stream);
  k_fill<<<(E + 255) / 256, 256, 0, stream>>>(srcp, dstp, rowptr, cur, col, E);
  k_bsum<<<1, 128, 0, stream>>>(bc, bl, bsum);

  // Y_all = bf16((x @ Wc) * dinv) for all N*T rows, one MFMA GEMM
  k_gemmx<<<MT / 128, 256, 0, stream>>>(x, Wc, dinv, (unsigned short*)Yall);
  // batched aggregation over all timesteps
  k_gatherT<<<(NN + 3) / 4, 256, 0, stream>>>(Yall, col, rowptr, dinv, agg);

  k_step0<<<(int)(((long)NN * DD + 255) / 256), 256, 0, stream>>>(agg, bsum, out);
  for (int t = 1; t < TT; ++t) {
    k_gemmh<<<(NN + 127) / 128, 256, 0, stream>>>(out + (long)(t - 1) * DD, Wl,
                                                  agg + (long)t * DD, bsum,
                                                  out + (long)t * DD);
  }
}

// Round 4
// 1849.698 us; speedup vs baseline: 1.8514x; 1.3102x over previous
//
#include <hip/hip_runtime.h>
#include <math.h>

#define NN 50000
#define TT 16
#define DD 128
#define MT (NN * TT)
#define TH 8  // t-chunk per gather pass
#define SCAN_B 1024
#define SCAN_NB ((NN + SCAN_B - 1) / SCAN_B)  // 49

typedef __attribute__((ext_vector_type(8))) short short8;
typedef __attribute__((ext_vector_type(4))) float f32x4;

// ---------- bf16 helpers ----------
static __device__ __forceinline__ unsigned short f2bf(float f) {
  unsigned u = __float_as_uint(f);
  u += 0x7FFFu + ((u >> 16) & 1u);  // RNE
  return (unsigned short)(u >> 16);
}
static __device__ __forceinline__ float bf_lo(unsigned v) {
  return __uint_as_float(v << 16);
}
static __device__ __forceinline__ float bf_hi(unsigned v) {
  return __uint_as_float(v & 0xffff0000u);
}

// ---------- graph preprocessing ----------

__global__ void k_deg_init(int* __restrict__ deg) {
  int i = blockIdx.x * blockDim.x + threadIdx.x;
  if (i < NN) deg[i] = 1;  // self loop
}

__global__ void k_deg_count(const int* __restrict__ dst, int* __restrict__ deg, int e) {
  int i = blockIdx.x * blockDim.x + threadIdx.x;
  if (i < e) atomicAdd(&deg[dst[i]], 1);
}

__global__ void k_dinv(const int* __restrict__ deg, float* __restrict__ dinv) {
  int i = blockIdx.x * blockDim.x + threadIdx.x;
  if (i < NN) dinv[i] = rsqrtf((float)deg[i]);
}

__global__ __launch_bounds__(SCAN_B) void k_scan1(const int* __restrict__ deg,
                                                  int* __restrict__ rowptr,
                                                  int* __restrict__ bsums) {
  __shared__ int sm[SCAN_B];
  int tid = threadIdx.x;
  int i = blockIdx.x * SCAN_B + tid;
  int v = (i < NN) ? (deg[i] - 1) : 0;
  sm[tid] = v;
  __syncthreads();
  for (int off = 1; off < SCAN_B; off <<= 1) {
    int t = (tid >= off) ? sm[tid - off] : 0;
    __syncthreads();
    sm[tid] += t;
    __syncthreads();
  }
  if (i < NN) rowptr[i] = sm[tid] - v;
  if (tid == SCAN_B - 1) bsums[blockIdx.x] = sm[tid];
}

__global__ void k_scan2(int* __restrict__ bsums) {
  __shared__ int sm[64];
  int tid = threadIdx.x;
  int v = (tid < SCAN_NB) ? bsums[tid] : 0;
  sm[tid] = v;
  __syncthreads();
  for (int off = 1; off < 64; off <<= 1) {
    int t = (tid >= off) ? sm[tid - off] : 0;
    __syncthreads();
    sm[tid] += t;
    __syncthreads();
  }
  if (tid < SCAN_NB) bsums[tid] = sm[tid] - v;
  if (tid == 63) bsums[SCAN_NB] = sm[63];
}

__global__ __launch_bounds__(SCAN_B) void k_scan3(int* __restrict__ rowptr,
                                                  const int* __restrict__ bsums) {
  int i = blockIdx.x * SCAN_B + threadIdx.x;
  if (i < NN) rowptr[i] += bsums[blockIdx.x];
  if (i == 0) rowptr[NN] = bsums[SCAN_NB];
}

__global__ void k_fill(const int* __restrict__ src, const int* __restrict__ dst,
                       const int* __restrict__ rowptr, int* __restrict__ cur,
                       int* __restrict__ col, int e) {
  int i = blockIdx.x * blockDim.x + threadIdx.x;
  if (i < e) {
    int d = dst[i];
    int slot = atomicAdd(&cur[d], 1);
    col[rowptr[d] + slot] = src[i];
  }
}

__global__ void k_bsum(const float* __restrict__ bc, const float* __restrict__ bl,
                       float* __restrict__ bsum) {
  int i = threadIdx.x;
  if (i < DD) bsum[i] = bc[i] + bl[i];
}

// W^T bf16 precompute: Wt[n*128+k] = bf16(W[k*128+n]); block = n, thread = k
__global__ void k_wprep(const float* __restrict__ Wc, const float* __restrict__ Wl,
                        unsigned short* __restrict__ Wct, unsigned short* __restrict__ Wlt) {
  int n = blockIdx.x, k = threadIdx.x;
  Wct[n * 128 + k] = f2bf(Wc[k * 128 + n]);
  Wlt[n * 128 + k] = f2bf(Wl[k * 128 + n]);
}

// ---------- GEMM-X (MFMA bf16, swapped operands): Y[row] = bf16((X[row]@Wc)*dinv[row>>4]) ----------
__global__ __launch_bounds__(256) void k_gemmx(
    const float* __restrict__ X, const unsigned short* __restrict__ Wct,
    const float* __restrict__ dinv, unsigned* __restrict__ Yall)
{
  __shared__ unsigned short sA[128 * 136];  // sA[r][k], pad 136
  const int tid = threadIdx.x;
  const long row0 = (long)blockIdx.x * 128;

  {
    int r = tid >> 1, half = tid & 1;
    const float* ap = X + (row0 + r) * 128 + half * 64;
    unsigned short* dstp = &sA[r * 136 + half * 64];
    #pragma unroll
    for (int i = 0; i < 16; ++i) {
      float4 v = *(const float4*)(ap + i * 4);
      unsigned u0 = (unsigned)f2bf(v.x) | ((unsigned)f2bf(v.y) << 16);
      unsigned u1 = (unsigned)f2bf(v.z) | ((unsigned)f2bf(v.w) << 16);
      *(uint2*)(dstp + i * 4) = make_uint2(u0, u1);
    }
  }
  __syncthreads();

  const int w = tid >> 6, l = tid & 63;
  const int lr = l & 15;
  const int lk = (l >> 4) << 3;
  f32x4 acc[2][8];
  #pragma unroll
  for (int i = 0; i < 2; ++i)
    #pragma unroll
    for (int n = 0; n < 8; ++n) acc[i][n] = (f32x4){0.f, 0.f, 0.f, 0.f};

  #pragma unroll
  for (int kg = 0; kg < 4; ++kg) {
    int kb = kg * 32 + lk;
    short8 a0 = *(const short8*)&sA[(w * 32 + lr) * 136 + kb];
    short8 a1 = *(const short8*)&sA[(w * 32 + 16 + lr) * 136 + kb];
    #pragma unroll
    for (int n = 0; n < 8; ++n) {
      short8 b = *(const short8*)&Wct[(n * 16 + lr) * 128 + kb];
      // swapped: D[m=wcol][n'=xrow]; lane: xrow=l&15, wcol=(l>>4)*4+reg
      acc[0][n] = __builtin_amdgcn_mfma_f32_16x16x32_bf16(b, a0, acc[0][n], 0, 0, 0);
      acc[1][n] = __builtin_amdgcn_mfma_f32_16x16x32_bf16(b, a1, acc[1][n], 0, 0, 0);
    }
  }

  const int wb = (l >> 4) * 4;
  #pragma unroll
  for (int i = 0; i < 2; ++i) {
    long row = row0 + w * 32 + i * 16 + lr;
    float s = dinv[row >> 4];  // row = node*16+t, all 16 rows of tile = same node
    #pragma unroll
    for (int n = 0; n < 8; ++n) {
      int c = n * 16 + wb;
      unsigned u0 = (unsigned)f2bf(acc[i][n][0] * s) | ((unsigned)f2bf(acc[i][n][1] * s) << 16);
      unsigned u1 = (unsigned)f2bf(acc[i][n][2] * s) | ((unsigned)f2bf(acc[i][n][3] * s) << 16);
      *(uint2*)(Yall + row * 64 + (c >> 1)) = make_uint2(u0, u1);
    }
  }
}

// ---------- gather, one t-chunk of 8: aggbf[n][t0+t] = bf16(dinv[n]*(sum_src y + y[n])) ----------
__global__ __launch_bounds__(256) void k_gatherT(
    const unsigned* __restrict__ Yall, const int* __restrict__ col,
    const int* __restrict__ rowptr, const float* __restrict__ dinv,
    unsigned* __restrict__ aggbf, int t0)
{
  int wave = threadIdx.x >> 6, lane = threadIdx.x & 63;
  int n = blockIdx.x * 4 + wave;
  if (n >= NN) return;
  int beg = rowptr[n], end = rowptr[n + 1];
  float ax[TH], ay[TH];
  {
    const unsigned* sp = Yall + ((long)n * TT + t0) * 64 + lane;  // self loop
    #pragma unroll
    for (int t = 0; t < TH; ++t) { unsigned v = sp[t * 64]; ax[t] = bf_lo(v); ay[t] = bf_hi(v); }
  }
  int j = beg;
  for (; j + 2 <= end; j += 2) {
    int s0 = col[j], s1 = col[j + 1];
    const unsigned* p0 = Yall + ((long)s0 * TT + t0) * 64 + lane;
    const unsigned* p1 = Yall + ((long)s1 * TT + t0) * 64 + lane;
    unsigned v0[TH], v1[TH];
    #pragma unroll
    for (int t = 0; t < TH; ++t) v0[t] = p0[t * 64];
    #pragma unroll
    for (int t = 0; t < TH; ++t) v1[t] = p1[t * 64];
    #pragma unroll
    for (int t = 0; t < TH; ++t) {
      ax[t] += bf_lo(v0[t]) + bf_lo(v1[t]);
      ay[t] += bf_hi(v0[t]) + bf_hi(v1[t]);
    }
  }
  if (j < end) {
    const unsigned* p0 = Yall + ((long)col[j] * TT + t0) * 64 + lane;
    #pragma unroll
    for (int t = 0; t < TH; ++t) { unsigned v = p0[t * 64]; ax[t] += bf_lo(v); ay[t] += bf_hi(v); }
  }
  float di = dinv[n];
  unsigned* ap = aggbf + ((long)n * TT + t0) * 64 + lane;
  #pragma unroll
  for (int t = 0; t < TH; ++t) {
    unsigned u = (unsigned)f2bf(di * ax[t]) | ((unsigned)f2bf(di * ay[t]) << 16);
    __builtin_nontemporal_store(u, ap + t * 64);
  }
}

// ---------- recurrence GEMM (MFMA bf16): out_t = tanh(h_{t-1}@Wl + agg_t + bsum) ----------
__global__ __launch_bounds__(256) void k_gemmh(
    const unsigned* __restrict__ hprev,      // [NN][64] uints (bf16 h_{t-1})
    const unsigned short* __restrict__ Wlt,  // [n][k] bf16 W_lin^T
    const unsigned* __restrict__ aggbf,
    const float* __restrict__ bsum,
    float* __restrict__ out, unsigned* __restrict__ hnew, int t)
{
  __shared__ unsigned short sA[128 * 136];
  const int tid = threadIdx.x;
  const int row0 = blockIdx.x * 128;

  {
    int r = tid >> 1, half = tid & 1;
    int row = row0 + r;
    const uint4* sp = (const uint4*)(hprev + (long)row * 64 + half * 32);
    unsigned short* dp = &sA[r * 136 + half * 64];
    #pragma unroll
    for (int i = 0; i < 8; ++i) {
      uint4 v = make_uint4(0, 0, 0, 0);
      if (row < NN) v = sp[i];
      *(uint4*)(dp + i * 8) = v;
    }
  }
  __syncthreads();

  const int w = tid >> 6, l = tid & 63;
  const int lr = l & 15;
  const int lk = (l >> 4) << 3;
  f32x4 acc[2][8];
  #pragma unroll
  for (int i = 0; i < 2; ++i)
    #pragma unroll
    for (int n = 0; n < 8; ++n) acc[i][n] = (f32x4){0.f, 0.f, 0.f, 0.f};

  #pragma unroll
  for (int kg = 0; kg < 4; ++kg) {
    int kb = kg * 32 + lk;
    short8 a0 = *(const short8*)&sA[(w * 32 + lr) * 136 + kb];
    short8 a1 = *(const short8*)&sA[(w * 32 + 16 + lr) * 136 + kb];
    #pragma unroll
    for (int n = 0; n < 8; ++n) {
      short8 b = *(const short8*)&Wlt[(n * 16 + lr) * 128 + kb];
      acc[0][n] = __builtin_amdgcn_mfma_f32_16x16x32_bf16(b, a0, acc[0][n], 0, 0, 0);
      acc[1][n] = __builtin_amdgcn_mfma_f32_16x16x32_bf16(b, a1, acc[1][n], 0, 0, 0);
    }
  }

  const int wb = (l >> 4) * 4;
  #pragma unroll
  for (int i = 0; i < 2; ++i) {
    int row = row0 + w * 32 + i * 16 + lr;
    if (row >= NN) continue;
    #pragma unroll
    for (int n = 0; n < 8; ++n) {
      int c = n * 16 + wb;
      uint2 ag = *(const uint2*)(aggbf + ((long)row * TT + t) * 64 + (c >> 1));
      float4 bs = *(const float4*)&bsum[c];
      float o0 = tanhf(acc[i][n][0] + bf_lo(ag.x) + bs.x);
      float o1 = tanhf(acc[i][n][1] + bf_hi(ag.x) + bs.y);
      float o2 = tanhf(acc[i][n][2] + bf_lo(ag.y) + bs.z);
      float o3 = tanhf(acc[i][n][3] + bf_hi(ag.y) + bs.w);
      *(float4*)(out + ((long)row * TT + t) * 128 + c) = make_float4(o0, o1, o2, o3);
      unsigned u0 = (unsigned)f2bf(o0) | ((unsigned)f2bf(o1) << 16);
      unsigned u1 = (unsigned)f2bf(o2) | ((unsigned)f2bf(o3) << 16);
      *(uint2*)(hnew + (long)row * 64 + (c >> 1)) = make_uint2(u0, u1);
    }
  }
}

// t = 0: out_0 = tanh(agg_0 + bsum); also seed hbf[0]
__global__ void k_step0(const unsigned* __restrict__ aggbf, const float* __restrict__ bsum,
                        float* __restrict__ out, unsigned* __restrict__ h0) {
  long i = (long)blockIdx.x * blockDim.x + threadIdx.x;  // one uint (2 elems)
  if (i >= (long)NN * 64) return;
  long n = i >> 6;
  int c2 = (int)(i & 63);
  unsigned ag = aggbf[n * (TT * 64) + c2];
  float o0 = tanhf(bf_lo(ag) + bsum[2 * c2]);
  float o1 = tanhf(bf_hi(ag) + bsum[2 * c2 + 1]);
  *(float2*)(out + n * (TT * DD) + 2 * c2) = make_float2(o0, o1);
  h0[n * 64 + c2] = (unsigned)f2bf(o0) | ((unsigned)f2bf(o1) << 16);
}

extern "C" void kernel_launch(void* const* d_in, const int* in_sizes, int n_in,
                              void* d_out, int out_size, void* d_ws, size_t ws_size,
                              hipStream_t stream) {
  const float* x  = (const float*)d_in[0];
  const int*   ei = (const int*)d_in[1];
  const float* Wc = (const float*)d_in[2];
  const float* bc = (const float*)d_in[3];
  const float* Wl = (const float*)d_in[4];
  const float* bl = (const float*)d_in[5];
  float* out = (float*)d_out;
  const int E = in_sizes[1] / 2;
  const int* srcp = ei;
  const int* dstp = ei + E;

  char* w = (char*)d_ws;
  auto alloc = [&](size_t bytes) {
    char* p = w;
    w += (bytes + 255) & ~(size_t)255;
    return p;
  };
  int*            deg    = (int*)alloc(sizeof(int) * NN);
  float*          dinv   = (float*)alloc(sizeof(float) * NN);
  int*            rowptr = (int*)alloc(sizeof(int) * (NN + 1));
  int*            cur    = (int*)alloc(sizeof(int) * NN);
  int*            bsums  = (int*)alloc(sizeof(int) * (SCAN_NB + 1));
  int*            col    = (int*)alloc(sizeof(int) * (size_t)E);
  unsigned*       Yall   = (unsigned*)alloc(sizeof(unsigned) * (size_t)MT * 64);  // 204.8 MB
  unsigned*       aggbf  = (unsigned*)alloc(sizeof(unsigned) * (size_t)MT * 64);  // 204.8 MB
  unsigned*       hbf0   = (unsigned*)alloc(sizeof(unsigned) * (size_t)NN * 64);  // 12.8 MB
  unsigned*       hbf1   = (unsigned*)alloc(sizeof(unsigned) * (size_t)NN * 64);  // 12.8 MB
  float*          bsum   = (float*)alloc(sizeof(float) * DD);
  unsigned short* Wct    = (unsigned short*)alloc(sizeof(unsigned short) * 128 * 128);
  unsigned short* Wlt    = (unsigned short*)alloc(sizeof(unsigned short) * 128 * 128);

  k_deg_init<<<(NN + 255) / 256, 256, 0, stream>>>(deg);
  k_deg_count<<<(E + 255) / 256, 256, 0, stream>>>(dstp, deg, E);
  k_dinv<<<(NN + 255) / 256, 256, 0, stream>>>(deg, dinv);
  k_scan1<<<SCAN_NB, SCAN_B, 0, stream>>>(deg, rowptr, bsums);
  k_scan2<<<1, 64, 0, stream>>>(bsums);
  k_scan3<<<SCAN_NB, SCAN_B, 0, stream>>>(rowptr, bsums);
  hipMemsetAsync(cur, 0, sizeof(int) * NN, stream);
  k_fill<<<(E + 255) / 256, 256, 0, stream>>>(srcp, dstp, rowptr, cur, col, E);
  k_bsum<<<1, 128, 0, stream>>>(bc, bl, bsum);
  k_wprep<<<128, 128, 0, stream>>>(Wc, Wl, Wct, Wlt);

  // Y_all = bf16((x @ Wc) * dinv_src) for all N*T rows
  k_gemmx<<<MT / 128, 256, 0, stream>>>(x, Wct, dinv, Yall);
  // aggregation in two t-half passes (per-pass working set 102 MB -> L3-resident)
  k_gatherT<<<(NN + 3) / 4, 256, 0, stream>>>(Yall, col, rowptr, dinv, aggbf, 0);
  k_gatherT<<<(NN + 3) / 4, 256, 0, stream>>>(Yall, col, rowptr, dinv, aggbf, TH);

  k_step0<<<(int)(((long)NN * 64 + 255) / 256), 256, 0, stream>>>(aggbf, bsum, out, hbf0);
  for (int t = 1; t < TT; ++t) {
    unsigned* hprev = (t & 1) ? hbf0 : hbf1;
    unsigned* hnew  = (t & 1) ? hbf1 : hbf0;
    k_gemmh<<<(NN + 127) / 128, 256, 0, stream>>>(hprev, Wlt, aggbf, bsum, out, hnew, t);
  }
}

// Round 6
// 1758.472 us; speedup vs baseline: 1.9475x; 1.0519x over previous
//
#include <hip/hip_runtime.h>
#include <math.h>

#define NN 50000
#define TT 16
#define DD 128
#define MT (NN * TT)
#define TH 2  // t-chunk per gather pass (working set 25.6MB read + 25.6MB write)
#define SCAN_B 1024
#define SCAN_NB ((NN + SCAN_B - 1) / SCAN_B)  // 49

typedef __attribute__((ext_vector_type(8))) short short8;
typedef __attribute__((ext_vector_type(4))) float f32x4;
typedef __attribute__((ext_vector_type(2))) unsigned u32x2;

// ---------- bf16 helpers ----------
static __device__ __forceinline__ unsigned short f2bf(float f) {
  unsigned u = __float_as_uint(f);
  u += 0x7FFFu + ((u >> 16) & 1u);  // RNE
  return (unsigned short)(u >> 16);
}
static __device__ __forceinline__ float bf_lo(unsigned v) {
  return __uint_as_float(v << 16);
}
static __device__ __forceinline__ float bf_hi(unsigned v) {
  return __uint_as_float(v & 0xffff0000u);
}

// ---------- graph preprocessing ----------

__global__ void k_deg_init(int* __restrict__ deg) {
  int i = blockIdx.x * blockDim.x + threadIdx.x;
  if (i < NN) deg[i] = 1;  // self loop
}

__global__ void k_deg_count(const int* __restrict__ dst, int* __restrict__ deg, int e) {
  int i = blockIdx.x * blockDim.x + threadIdx.x;
  if (i < e) atomicAdd(&deg[dst[i]], 1);
}

__global__ void k_dinv(const int* __restrict__ deg, float* __restrict__ dinv) {
  int i = blockIdx.x * blockDim.x + threadIdx.x;
  if (i < NN) dinv[i] = rsqrtf((float)deg[i]);
}

__global__ __launch_bounds__(SCAN_B) void k_scan1(const int* __restrict__ deg,
                                                  int* __restrict__ rowptr,
                                                  int* __restrict__ bsums) {
  __shared__ int sm[SCAN_B];
  int tid = threadIdx.x;
  int i = blockIdx.x * SCAN_B + tid;
  int v = (i < NN) ? (deg[i] - 1) : 0;
  sm[tid] = v;
  __syncthreads();
  for (int off = 1; off < SCAN_B; off <<= 1) {
    int t = (tid >= off) ? sm[tid - off] : 0;
    __syncthreads();
    sm[tid] += t;
    __syncthreads();
  }
  if (i < NN) rowptr[i] = sm[tid] - v;
  if (tid == SCAN_B - 1) bsums[blockIdx.x] = sm[tid];
}

__global__ void k_scan2(int* __restrict__ bsums) {
  __shared__ int sm[64];
  int tid = threadIdx.x;
  int v = (tid < SCAN_NB) ? bsums[tid] : 0;
  sm[tid] = v;
  __syncthreads();
  for (int off = 1; off < 64; off <<= 1) {
    int t = (tid >= off) ? sm[tid - off] : 0;
    __syncthreads();
    sm[tid] += t;
    __syncthreads();
  }
  if (tid < SCAN_NB) bsums[tid] = sm[tid] - v;
  if (tid == 63) bsums[SCAN_NB] = sm[63];
}

__global__ __launch_bounds__(SCAN_B) void k_scan3(int* __restrict__ rowptr,
                                                  const int* __restrict__ bsums) {
  int i = blockIdx.x * SCAN_B + threadIdx.x;
  if (i < NN) rowptr[i] += bsums[blockIdx.x];
  if (i == 0) rowptr[NN] = bsums[SCAN_NB];
}

__global__ void k_fill(const int* __restrict__ src, const int* __restrict__ dst,
                       const int* __restrict__ rowptr, int* __restrict__ cur,
                       int* __restrict__ col, int e) {
  int i = blockIdx.x * blockDim.x + threadIdx.x;
  if (i < e) {
    int d = dst[i];
    int slot = atomicAdd(&cur[d], 1);
    col[rowptr[d] + slot] = src[i];
  }
}

__global__ void k_bsum(const float* __restrict__ bc, const float* __restrict__ bl,
                       float* __restrict__ bsum) {
  int i = threadIdx.x;
  if (i < DD) bsum[i] = bc[i] + bl[i];
}

// W^T bf16 precompute: Wt[n*128+k] = bf16(W[k*128+n]); block = n, thread = k
__global__ void k_wprep(const float* __restrict__ Wc, const float* __restrict__ Wl,
                        unsigned short* __restrict__ Wct, unsigned short* __restrict__ Wlt) {
  int n = blockIdx.x, k = threadIdx.x;
  Wct[n * 128 + k] = f2bf(Wc[k * 128 + n]);
  Wlt[n * 128 + k] = f2bf(Wl[k * 128 + n]);
}

// ---------- GEMM-X (MFMA bf16, swapped operands): Y[row] = bf16((X[row]@Wc)*dinv[row>>4]) ----------
__global__ __launch_bounds__(256) void k_gemmx(
    const float* __restrict__ X, const unsigned short* __restrict__ Wct,
    const float* __restrict__ dinv, unsigned* __restrict__ Yall)
{
  __shared__ unsigned short sA[128 * 136];  // sA[r][k], pad 136
  const int tid = threadIdx.x;
  const long row0 = (long)blockIdx.x * 128;

  {
    int r = tid >> 1, half = tid & 1;
    const float* ap = X + (row0 + r) * 128 + half * 64;
    unsigned short* dstp = &sA[r * 136 + half * 64];
    #pragma unroll
    for (int i = 0; i < 16; ++i) {
      float4 v = *(const float4*)(ap + i * 4);
      unsigned u0 = (unsigned)f2bf(v.x) | ((unsigned)f2bf(v.y) << 16);
      unsigned u1 = (unsigned)f2bf(v.z) | ((unsigned)f2bf(v.w) << 16);
      *(uint2*)(dstp + i * 4) = make_uint2(u0, u1);
    }
  }
  __syncthreads();

  const int w = tid >> 6, l = tid & 63;
  const int lr = l & 15;
  const int lk = (l >> 4) << 3;
  f32x4 acc[2][8];
  #pragma unroll
  for (int i = 0; i < 2; ++i)
    #pragma unroll
    for (int n = 0; n < 8; ++n) acc[i][n] = (f32x4){0.f, 0.f, 0.f, 0.f};

  #pragma unroll
  for (int kg = 0; kg < 4; ++kg) {
    int kb = kg * 32 + lk;
    short8 a0 = *(const short8*)&sA[(w * 32 + lr) * 136 + kb];
    short8 a1 = *(const short8*)&sA[(w * 32 + 16 + lr) * 136 + kb];
    #pragma unroll
    for (int n = 0; n < 8; ++n) {
      short8 b = *(const short8*)&Wct[(n * 16 + lr) * 128 + kb];
      // swapped: lane holds xrow = l&15, wcol = (l>>4)*4+reg
      acc[0][n] = __builtin_amdgcn_mfma_f32_16x16x32_bf16(b, a0, acc[0][n], 0, 0, 0);
      acc[1][n] = __builtin_amdgcn_mfma_f32_16x16x32_bf16(b, a1, acc[1][n], 0, 0, 0);
    }
  }

  const int wb = (l >> 4) * 4;
  #pragma unroll
  for (int i = 0; i < 2; ++i) {
    long row = row0 + w * 32 + i * 16 + lr;
    float s = dinv[row >> 4];  // row = node*16+t
    #pragma unroll
    for (int n = 0; n < 8; ++n) {
      int c = n * 16 + wb;
      unsigned u0 = (unsigned)f2bf(acc[i][n][0] * s) | ((unsigned)f2bf(acc[i][n][1] * s) << 16);
      unsigned u1 = (unsigned)f2bf(acc[i][n][2] * s) | ((unsigned)f2bf(acc[i][n][3] * s) << 16);
      *(uint2*)(Yall + row * 64 + (c >> 1)) = make_uint2(u0, u1);
    }
  }
}

// ---------- gather, t-chunk of 2 ----------
// uint2 per lane: 512B wave-load spans rows (n,t0) and (n,t0+1).
__global__ __launch_bounds__(256) void k_gatherT(
    const unsigned* __restrict__ Yall, const int* __restrict__ col,
    const int* __restrict__ rowptr, const float* __restrict__ dinv,
    unsigned* __restrict__ aggbf, int t0)
{
  int wave = threadIdx.x >> 6, lane = threadIdx.x & 63;
  int n = blockIdx.x * 4 + wave;
  if (n >= NN) return;
  int beg = rowptr[n], end = rowptr[n + 1];

  float f0, f1, f2, f3;
  {
    u32x2 v = *((const u32x2*)(Yall + ((long)n * TT + t0) * 64) + lane);  // self loop
    f0 = bf_lo(v.x); f1 = bf_hi(v.x); f2 = bf_lo(v.y); f3 = bf_hi(v.y);
  }
  float g0 = 0, g1 = 0, g2 = 0, g3 = 0;
  float p0 = 0, p1 = 0, p2 = 0, p3 = 0;
  float q0 = 0, q1 = 0, q2 = 0, q3 = 0;
  int j = beg;
  for (; j + 4 <= end; j += 4) {
    int s0 = col[j], s1 = col[j + 1], s2 = col[j + 2], s3 = col[j + 3];
    u32x2 v0 = *((const u32x2*)(Yall + ((long)s0 * TT + t0) * 64) + lane);
    u32x2 v1 = *((const u32x2*)(Yall + ((long)s1 * TT + t0) * 64) + lane);
    u32x2 v2 = *((const u32x2*)(Yall + ((long)s2 * TT + t0) * 64) + lane);
    u32x2 v3 = *((const u32x2*)(Yall + ((long)s3 * TT + t0) * 64) + lane);
    f0 += bf_lo(v0.x); f1 += bf_hi(v0.x); f2 += bf_lo(v0.y); f3 += bf_hi(v0.y);
    g0 += bf_lo(v1.x); g1 += bf_hi(v1.x); g2 += bf_lo(v1.y); g3 += bf_hi(v1.y);
    p0 += bf_lo(v2.x); p1 += bf_hi(v2.x); p2 += bf_lo(v2.y); p3 += bf_hi(v2.y);
    q0 += bf_lo(v3.x); q1 += bf_hi(v3.x); q2 += bf_lo(v3.y); q3 += bf_hi(v3.y);
  }
  for (; j < end; ++j) {
    u32x2 v = *((const u32x2*)(Yall + ((long)col[j] * TT + t0) * 64) + lane);
    f0 += bf_lo(v.x); f1 += bf_hi(v.x); f2 += bf_lo(v.y); f3 += bf_hi(v.y);
  }
  float di = dinv[n];
  f0 = di * (f0 + g0 + p0 + q0);
  f1 = di * (f1 + g1 + p1 + q1);
  f2 = di * (f2 + g2 + p2 + q2);
  f3 = di * (f3 + g3 + p3 + q3);
  u32x2 u;
  u.x = (unsigned)f2bf(f0) | ((unsigned)f2bf(f1) << 16);
  u.y = (unsigned)f2bf(f2) | ((unsigned)f2bf(f3) << 16);
  __builtin_nontemporal_store(u, (u32x2*)(aggbf + ((long)n * TT + t0) * 64) + lane);
}

// ---------- recurrence GEMM (MFMA bf16): out_t = tanh(h_{t-1}@Wl + agg_t + bsum) ----------
__global__ __launch_bounds__(256) void k_gemmh(
    const unsigned* __restrict__ hprev,      // [NN][64] uints (bf16 h_{t-1})
    const unsigned short* __restrict__ Wlt,  // [n][k] bf16 W_lin^T
    const unsigned* __restrict__ aggbf,
    const float* __restrict__ bsum,
    float* __restrict__ out, unsigned* __restrict__ hnew, int t)
{
  __shared__ unsigned short sA[128 * 136];
  const int tid = threadIdx.x;
  const int row0 = blockIdx.x * 128;

  {
    int r = tid >> 1, half = tid & 1;
    int row = row0 + r;
    const uint4* sp = (const uint4*)(hprev + (long)row * 64 + half * 32);
    unsigned short* dp = &sA[r * 136 + half * 64];
    #pragma unroll
    for (int i = 0; i < 8; ++i) {
      uint4 v = make_uint4(0, 0, 0, 0);
      if (row < NN) v = sp[i];
      *(uint4*)(dp + i * 8) = v;
    }
  }
  __syncthreads();

  const int w = tid >> 6, l = tid & 63;
  const int lr = l & 15;
  const int lk = (l >> 4) << 3;
  f32x4 acc[2][8];
  #pragma unroll
  for (int i = 0; i < 2; ++i)
    #pragma unroll
    for (int n = 0; n < 8; ++n) acc[i][n] = (f32x4){0.f, 0.f, 0.f, 0.f};

  #pragma unroll
  for (int kg = 0; kg < 4; ++kg) {
    int kb = kg * 32 + lk;
    short8 a0 = *(const short8*)&sA[(w * 32 + lr) * 136 + kb];
    short8 a1 = *(const short8*)&sA[(w * 32 + 16 + lr) * 136 + kb];
    #pragma unroll
    for (int n = 0; n < 8; ++n) {
      short8 b = *(const short8*)&Wlt[(n * 16 + lr) * 128 + kb];
      acc[0][n] = __builtin_amdgcn_mfma_f32_16x16x32_bf16(b, a0, acc[0][n], 0, 0, 0);
      acc[1][n] = __builtin_amdgcn_mfma_f32_16x16x32_bf16(b, a1, acc[1][n], 0, 0, 0);
    }
  }

  const int wb = (l >> 4) * 4;
  #pragma unroll
  for (int i = 0; i < 2; ++i) {
    int row = row0 + w * 32 + i * 16 + lr;
    if (row >= NN) continue;
    #pragma unroll
    for (int n = 0; n < 8; ++n) {
      int c = n * 16 + wb;
      uint2 ag = *(const uint2*)(aggbf + ((long)row * TT + t) * 64 + (c >> 1));
      float4 bs = *(const float4*)&bsum[c];
      float o0 = tanhf(acc[i][n][0] + bf_lo(ag.x) + bs.x);
      float o1 = tanhf(acc[i][n][1] + bf_hi(ag.x) + bs.y);
      float o2 = tanhf(acc[i][n][2] + bf_lo(ag.y) + bs.z);
      float o3 = tanhf(acc[i][n][3] + bf_hi(ag.y) + bs.w);
      *(float4*)(out + ((long)row * TT + t) * 128 + c) = make_float4(o0, o1, o2, o3);
      unsigned u0 = (unsigned)f2bf(o0) | ((unsigned)f2bf(o1) << 16);
      unsigned u1 = (unsigned)f2bf(o2) | ((unsigned)f2bf(o3) << 16);
      *(uint2*)(hnew + (long)row * 64 + (c >> 1)) = make_uint2(u0, u1);
    }
  }
}

// t = 0: out_0 = tanh(agg_0 + bsum); also seed hbf[0]
__global__ void k_step0(const unsigned* __restrict__ aggbf, const float* __restrict__ bsum,
                        float* __restrict__ out, unsigned* __restrict__ h0) {
  long i = (long)blockIdx.x * blockDim.x + threadIdx.x;  // one uint (2 elems)
  if (i >= (long)NN * 64) return;
  long n = i >> 6;
  int c2 = (int)(i & 63);
  unsigned ag = aggbf[n * (TT * 64) + c2];
  float o0 = tanhf(bf_lo(ag) + bsum[2 * c2]);
  float o1 = tanhf(bf_hi(ag) + bsum[2 * c2 + 1]);
  *(float2*)(out + n * (TT * DD) + 2 * c2) = make_float2(o0, o1);
  h0[n * 64 + c2] = (unsigned)f2bf(o0) | ((unsigned)f2bf(o1) << 16);
}

extern "C" void kernel_launch(void* const* d_in, const int* in_sizes, int n_in,
                              void* d_out, int out_size, void* d_ws, size_t ws_size,
                              hipStream_t stream) {
  const float* x  = (const float*)d_in[0];
  const int*   ei = (const int*)d_in[1];
  const float* Wc = (const float*)d_in[2];
  const float* bc = (const float*)d_in[3];
  const float* Wl = (const float*)d_in[4];
  const float* bl = (const float*)d_in[5];
  float* out = (float*)d_out;
  const int E = in_sizes[1] / 2;
  const int* srcp = ei;
  const int* dstp = ei + E;

  char* w = (char*)d_ws;
  auto alloc = [&](size_t bytes) {
    char* p = w;
    w += (bytes + 255) & ~(size_t)255;
    return p;
  };
  int*            deg    = (int*)alloc(sizeof(int) * NN);
  float*          dinv   = (float*)alloc(sizeof(float) * NN);
  int*            rowptr = (int*)alloc(sizeof(int) * (NN + 1));
  int*            cur    = (int*)alloc(sizeof(int) * NN);
  int*            bsums  = (int*)alloc(sizeof(int) * (SCAN_NB + 1));
  int*            col    = (int*)alloc(sizeof(int) * (size_t)E);
  unsigned*       Yall   = (unsigned*)alloc(sizeof(unsigned) * (size_t)MT * 64);  // 204.8 MB
  unsigned*       aggbf  = (unsigned*)alloc(sizeof(unsigned) * (size_t)MT * 64);  // 204.8 MB
  unsigned*       hbf0   = (unsigned*)alloc(sizeof(unsigned) * (size_t)NN * 64);  // 12.8 MB
  unsigned*       hbf1   = (unsigned*)alloc(sizeof(unsigned) * (size_t)NN * 64);  // 12.8 MB
  float*          bsum   = (float*)alloc(sizeof(float) * DD);
  unsigned short* Wct    = (unsigned short*)alloc(sizeof(unsigned short) * 128 * 128);
  unsigned short* Wlt    = (unsigned short*)alloc(sizeof(unsigned short) * 128 * 128);

  k_deg_init<<<(NN + 255) / 256, 256, 0, stream>>>(deg);
  k_deg_count<<<(E + 255) / 256, 256, 0, stream>>>(dstp, deg, E);
  k_dinv<<<(NN + 255) / 256, 256, 0, stream>>>(deg, dinv);
  k_scan1<<<SCAN_NB, SCAN_B, 0, stream>>>(deg, rowptr, bsums);
  k_scan2<<<1, 64, 0, stream>>>(bsums);
  k_scan3<<<SCAN_NB, SCAN_B, 0, stream>>>(rowptr, bsums);
  (void)hipMemsetAsync(cur, 0, sizeof(int) * NN, stream);
  k_fill<<<(E + 255) / 256, 256, 0, stream>>>(srcp, dstp, rowptr, cur, col, E);
  k_bsum<<<1, 128, 0, stream>>>(bc, bl, bsum);
  k_wprep<<<128, 128, 0, stream>>>(Wc, Wl, Wct, Wlt);

  // Y_all = bf16((x @ Wc) * dinv_src) for all N*T rows
  k_gemmx<<<MT / 128, 256, 0, stream>>>(x, Wct, dinv, Yall);
  // aggregation in 8 passes of 2 timesteps: per-pass footprint ~58MB << 256MB L3
  for (int t0 = 0; t0 < TT; t0 += TH)
    k_gatherT<<<(NN + 3) / 4, 256, 0, stream>>>(Yall, col, rowptr, dinv, aggbf, t0);

  k_step0<<<(int)(((long)NN * 64 + 255) / 256), 256, 0, stream>>>(aggbf, bsum, out, hbf0);
  for (int t = 1; t < TT; ++t) {
    unsigned* hprev = (t & 1) ? hbf0 : hbf1;
    unsigned* hnew  = (t & 1) ? hbf1 : hbf0;
    k_gemmh<<<(NN + 127) / 128, 256, 0, stream>>>(hprev, Wlt, aggbf, bsum, out, hnew, t);
  }
}